// Round 9
// baseline (102.625 us; speedup 1.0000x reference)
//
#include <hip/hip_runtime.h>
#include <hip/hip_bf16.h>

// TripletLoss B=4096 D=128 fp32. R9: register-resident MFMA Gram — NO LDS,
// NO barriers in phase1. For Gram (C = E·E^T) the MFMA B-operand lane layout
// equals the A-operand layout (both row-major row-fragments of Ebf), so each
// wave loads its 16 A-frags + 16 B-frags straight from global (L2-resident
// 1 MB Ebf) into VGPRs, batched per K-half. Waves fully independent: no
// stage->drain->barrier pipeline (the ~20 us structural cost of R5/R7/R8).
// Epilogue mines val = sq[j]-2g in registers, 4-step shfl fold, stores to
// per-(jblock,wc) partial planes (64 planes); phase2 folds 64/row,
// validity from sentinels, ticket finalize.

typedef __attribute__((ext_vector_type(8))) short short8;
typedef __attribute__((ext_vector_type(4))) float f32x4;

#define MARGIN_F 0.3f
#define NEG_BIG -3.4e38f
#define POS_BIG 3.4e38f

__device__ inline unsigned short f2bf(float x) {
    union { __hip_bfloat16 h; unsigned short u; } c;
    c.h = __float2bfloat16(x);
    return c.u;
}

// grid 512 x 256: 32 threads/row. bf16 convert + row norms + zero counters.
__global__ __launch_bounds__(256) void tl_prep(const float* __restrict__ E,
                                               unsigned short* __restrict__ Ebf,
                                               float* __restrict__ sqn,
                                               unsigned* __restrict__ cnt) {
    int t = blockIdx.x * 256 + threadIdx.x;
    if (t < 4) cnt[t] = 0u;
    int row = t >> 5;
    int kq = (t & 31) * 4;
    float4 v = *(const float4*)&E[(size_t)row * 128 + kq];
    float s = fmaf(v.x, v.x, fmaf(v.y, v.y, fmaf(v.z, v.z, v.w * v.w)));
    ushort4 h4;
    h4.x = f2bf(v.x); h4.y = f2bf(v.y); h4.z = f2bf(v.z); h4.w = f2bf(v.w);
    *(ushort4*)&Ebf[(size_t)row * 128 + kq] = h4;
#pragma unroll
    for (int m = 1; m < 32; m <<= 1) s += __shfl_xor(s, m);
    if ((t & 31) == 0) sqn[row] = s;
}

// grid (32,32) x 256. 4 waves in 2x2; wave tile 64x64 = 4x4 MFMA 16x16x32.
// No LDS, no __syncthreads. Frags loaded directly from global.
__global__ __launch_bounds__(256) void tl_phase1(const unsigned short* __restrict__ Ebf,
                                                 const int* __restrict__ labels,
                                                 const float* __restrict__ sqn,
                                                 float* __restrict__ pmp,
                                                 float* __restrict__ pmn) {
    const int tid = threadIdx.x;
    const int l = tid & 63, w = tid >> 6;
    const int wr = w >> 1, wc = w & 1;
    const int q = l >> 4, r16 = l & 15;
    const int i0 = blockIdx.x * 128, j0 = blockIdx.y * 128;

    // fragment bases: lane covers row (.. + r16), k-offset q*8
    const unsigned short* aB = Ebf + (size_t)(i0 + wr * 64 + r16) * 128 + q * 8;
    const unsigned short* bB = Ebf + (size_t)(j0 + wc * 64 + r16) * 128 + q * 8;

    // epilogue metadata
    int li[4][4], lj[4];
    float sj[4];
#pragma unroll
    for (int ti = 0; ti < 4; ++ti)
#pragma unroll
        for (int p = 0; p < 4; ++p)
            li[ti][p] = labels[i0 + wr * 64 + ti * 16 + q * 4 + p];
#pragma unroll
    for (int tj = 0; tj < 4; ++tj) {
        int cj = j0 + wc * 64 + tj * 16 + r16;
        lj[tj] = labels[cj];
        sj[tj] = sqn[cj];
    }

    f32x4 acc[4][4];
#pragma unroll
    for (int ti = 0; ti < 4; ++ti)
#pragma unroll
        for (int tj = 0; tj < 4; ++tj) acc[ti][tj] = (f32x4)0.0f;

#pragma unroll
    for (int kc = 0; kc < 2; ++kc) {
        short8 af[4][2], bf8[4][2];  // [t2][s]
#pragma unroll
        for (int t2 = 0; t2 < 4; ++t2)
#pragma unroll
            for (int s = 0; s < 2; ++s) {
                af[t2][s] = *(const short8*)(aB + (size_t)t2 * 16 * 128 + kc * 64 + s * 32);
                bf8[t2][s] = *(const short8*)(bB + (size_t)t2 * 16 * 128 + kc * 64 + s * 32);
            }
#pragma unroll
        for (int s = 0; s < 2; ++s)
#pragma unroll
            for (int ti = 0; ti < 4; ++ti)
#pragma unroll
                for (int tj = 0; tj < 4; ++tj)
                    acc[ti][tj] = __builtin_amdgcn_mfma_f32_16x16x32_bf16(
                        af[ti][s], bf8[tj][s], acc[ti][tj], 0, 0, 0);
    }

    // mine val = sq[j] - 2*g (monotone in d2 for fixed i)
    float mp[4][4], mn[4][4];
#pragma unroll
    for (int ti = 0; ti < 4; ++ti)
#pragma unroll
        for (int p = 0; p < 4; ++p) { mp[ti][p] = NEG_BIG; mn[ti][p] = POS_BIG; }
    const bool diagblk = (blockIdx.x == blockIdx.y);
#pragma unroll
    for (int tj = 0; tj < 4; ++tj) {
#pragma unroll
        for (int ti = 0; ti < 4; ++ti)
#pragma unroll
            for (int p = 0; p < 4; ++p) {
                float val = fmaf(-2.0f, acc[ti][tj][p], sj[tj]);
                bool same = (li[ti][p] == lj[tj]);
                bool self = diagblk &&
                    ((wr * 64 + ti * 16 + q * 4 + p) == (wc * 64 + tj * 16 + r16));
                mp[ti][p] = fmaxf(mp[ti][p], (same && !self) ? val : NEG_BIG);
                mn[ti][p] = fminf(mn[ti][p], same ? POS_BIG : val);
            }
    }

    // fold across the 16 column-lanes of each quad; store per-(jblock,wc) plane
    const int plane = blockIdx.y * 2 + wc;
#pragma unroll
    for (int ti = 0; ti < 4; ++ti)
#pragma unroll
        for (int p = 0; p < 4; ++p) {
            float a = mp[ti][p], b = mn[ti][p];
#pragma unroll
            for (int m = 1; m < 16; m <<= 1) {
                a = fmaxf(a, __shfl_xor(a, m));
                b = fminf(b, __shfl_xor(b, m));
            }
            if (r16 == 0) {
                int rrow = i0 + wr * 64 + ti * 16 + q * 4 + p;
                pmp[(size_t)plane * 4096 + rrow] = a;
                pmn[(size_t)plane * 4096 + rrow] = b;
            }
        }
}

// grid 16 x 256: fold 64 partials/row; validity from sentinels; ticket finalize.
__global__ __launch_bounds__(256) void tl_phase2(const float* __restrict__ pmp,
                                                 const float* __restrict__ pmn,
                                                 const float* __restrict__ sqn,
                                                 unsigned* __restrict__ cnt,
                                                 float* __restrict__ accum,
                                                 float* __restrict__ out) {
    __shared__ float sp[4], sv[4];
    int tid = threadIdx.x;
    int r = blockIdx.x * 256 + tid;
    float mp = NEG_BIG, mn = POS_BIG;
#pragma unroll
    for (int k = 0; k < 64; ++k) {
        mp = fmaxf(mp, pmp[(size_t)k * 4096 + r]);
        mn = fminf(mn, pmn[(size_t)k * 4096 + r]);
    }
    float si = sqn[r];
    bool valid = (mp > 0.5f * NEG_BIG) && (mn < 0.5f * POS_BIG);
    float hp = sqrtf(fmaxf(si + mp, 0.0f));
    float hn = sqrtf(fmaxf(si + mn, 0.0f));
    float pr = fmaxf(hp - hn + MARGIN_F, 0.0f);
    float s = valid ? pr : 0.0f;
    float n = valid ? 1.0f : 0.0f;
#pragma unroll
    for (int m = 1; m < 64; m <<= 1) {
        s += __shfl_xor(s, m);
        n += __shfl_xor(n, m);
    }
    if ((tid & 63) == 0) { sp[tid >> 6] = s; sv[tid >> 6] = n; }
    __syncthreads();
    if (tid == 0) {
        atomicAdd(&accum[0], sp[0] + sp[1] + sp[2] + sp[3]);
        atomicAdd(&accum[1], sv[0] + sv[1] + sv[2] + sv[3]);
        __threadfence();
        unsigned tk = atomicAdd(&cnt[2], 1u);
        if (tk == 15u) {
            float a = atomicAdd(&accum[0], 0.0f);  // coherent read
            float b = atomicAdd(&accum[1], 0.0f);
            out[0] = a / fmaxf(b, 1.0f);
        }
    }
}

extern "C" void kernel_launch(void* const* d_in, const int* in_sizes, int n_in,
                              void* d_out, int out_size, void* d_ws, size_t ws_size,
                              hipStream_t stream) {
    const float* E = (const float*)d_in[0];
    const int* labels = (const int*)d_in[1];
    float* out = (float*)d_out;

    // ws: Ebf 1 MB | pmp 1 MB (64 planes) | pmn 1 MB | sqn 16 KB | cnt/accum
    char* base = (char*)d_ws;
    unsigned short* Ebf = (unsigned short*)base;
    float* pmp = (float*)(base + (1u << 20));
    float* pmn = (float*)(base + (2u << 20));
    float* sqn = (float*)(base + (3u << 20));
    unsigned* cnt = (unsigned*)(base + (3u << 20) + (16u << 10));
    float* accum = (float*)(cnt + 8);

    tl_prep<<<512, 256, 0, stream>>>(E, Ebf, sqn, cnt);
    tl_phase1<<<dim3(32, 32), 256, 0, stream>>>(Ebf, labels, sqn, pmp, pmn);
    tl_phase2<<<16, 256, 0, stream>>>(pmp, pmn, sqn, cnt, accum, out);
}

// Round 10
// 81.684 us; speedup vs baseline: 1.2564x; 1.2564x over previous
//
#include <hip/hip_runtime.h>
#include <hip/hip_bf16.h>

// TripletLoss B=4096 D=128 fp32. R10: R5 structure (all-prefetch, both tiles
// LDS-staged, fine vmcnt + raw barrier, xor-swizzle) with 512-thread blocks:
// 8 waves (2 row x 4 col) on a 128x128 tile -> 16 waves/CU at 2 blocks/CU
// (double R5's latency-hiding TLP, same traffic). Wave tile 64x32 = 4x2
// MFMA 16x16x32, acc = 32 VGPR. Epilogue mines val = sq[j]-2g, folds via
// 128x64 LDS matrix (aliases staging) + 4-lane shfl, atomic-free partial
// stores (32 planes); phase2 folds 32/row, validity from sentinels.

typedef __attribute__((ext_vector_type(8))) short short8;
typedef __attribute__((ext_vector_type(4))) float f32x4;

#define MARGIN_F 0.3f
#define NEG_BIG -3.4e38f
#define POS_BIG 3.4e38f
// gfx9 waitcnt encoding: vmcnt[3:0]|[15:14], expcnt[6:4], lgkmcnt[11:8]
#define WAITVM(N) __builtin_amdgcn_s_waitcnt(((N)&15)|((((N)>>4)&3)<<14)|(7<<4)|(15<<8))

__device__ __forceinline__ void gl_lds16(const void* g, void* l) {
    __builtin_amdgcn_global_load_lds(
        (const __attribute__((address_space(1))) void*)g,
        (__attribute__((address_space(3))) void*)l, 16, 0, 0);
}

__device__ inline unsigned short f2bf(float x) {
    union { __hip_bfloat16 h; unsigned short u; } c;
    c.h = __float2bfloat16(x);
    return c.u;
}

// grid 512 x 256: 32 threads/row. bf16 convert + row norms + zero counters.
__global__ __launch_bounds__(256) void tl_prep(const float* __restrict__ E,
                                               unsigned short* __restrict__ Ebf,
                                               float* __restrict__ sqn,
                                               unsigned* __restrict__ cnt) {
    int t = blockIdx.x * 256 + threadIdx.x;
    if (t < 4) cnt[t] = 0u;
    int row = t >> 5;
    int kq = (t & 31) * 4;
    float4 v = *(const float4*)&E[(size_t)row * 128 + kq];
    float s = fmaf(v.x, v.x, fmaf(v.y, v.y, fmaf(v.z, v.z, v.w * v.w)));
    ushort4 h4;
    h4.x = f2bf(v.x); h4.y = f2bf(v.y); h4.z = f2bf(v.z); h4.w = f2bf(v.w);
    *(ushort4*)&Ebf[(size_t)row * 128 + kq] = h4;
#pragma unroll
    for (int m = 1; m < 32; m <<= 1) s += __shfl_xor(s, m);
    if ((t & 31) == 0) sqn[row] = s;
}

// grid (32,32) x 512 threads. 8 waves 2x4; wave tile 64x32 = 4x2 MFMA tiles.
// LDS per K-chunk per matrix: 128 rows x 64 bf16; chunk c of row r at slot
// c^(r&7) (staging lane-contiguous AND b128 frag reads conflict-free).
__global__ __launch_bounds__(512, 4) void tl_phase1(const unsigned short* __restrict__ Ebf,
                                                    const int* __restrict__ labels,
                                                    const float* __restrict__ sqn,
                                                    float* __restrict__ pmp,
                                                    float* __restrict__ pmn) {
    union SM {
        struct { unsigned short A[2][128 * 64]; unsigned short B[2][128 * 64]; } s;  // 64 KB
        struct { float mp[128][64]; float mn[128][64]; } f;                          // 64 KB
    };
    __shared__ __align__(16) SM sm;

    const int tid = threadIdx.x;
    const int l = tid & 63, w = tid >> 6;      // 8 waves
    const int wr = w >> 2, wc = w & 3;         // 2 x 4
    const int q = l >> 4, r16 = l & 15;
    const int i0 = blockIdx.x * 128, j0 = blockIdx.y * 128;

    // staging: slot s = t2*512 + w*64 + l (t2 in {0,1}); row=s>>3; chunk=(s&7)^(row&7)
    const unsigned short* gA[2];
    const unsigned short* gB[2];
#pragma unroll
    for (int t2 = 0; t2 < 2; ++t2) {
        int s = t2 * 512 + tid;
        int row = s >> 3, ch = (s & 7) ^ (row & 7);
        gA[t2] = Ebf + (size_t)(i0 + row) * 128 + ch * 8;
        gB[t2] = Ebf + (size_t)(j0 + row) * 128 + ch * 8;
    }
    // issue all 8 staging ops: kc0 (4) then kc1 (4)
#pragma unroll
    for (int kc = 0; kc < 2; ++kc)
#pragma unroll
        for (int t2 = 0; t2 < 2; ++t2) {
            gl_lds16(gA[t2] + kc * 64, &sm.s.A[kc][(t2 * 512 + w * 64) * 8]);
            gl_lds16(gB[t2] + kc * 64, &sm.s.B[kc][(t2 * 512 + w * 64) * 8]);
        }

    // epilogue metadata (independent of staging)
    int li[4][4], lj[2];
    float sj[2];
#pragma unroll
    for (int ti = 0; ti < 4; ++ti)
#pragma unroll
        for (int p = 0; p < 4; ++p)
            li[ti][p] = labels[i0 + wr * 64 + ti * 16 + q * 4 + p];
#pragma unroll
    for (int tj = 0; tj < 2; ++tj) {
        int cj = j0 + wc * 32 + tj * 16 + r16;
        lj[tj] = labels[cj];
        sj[tj] = sqn[cj];
    }

    f32x4 acc[4][2];
#pragma unroll
    for (int ti = 0; ti < 4; ++ti)
#pragma unroll
        for (int tj = 0; tj < 2; ++tj) acc[ti][tj] = (f32x4)0.0f;

#pragma unroll
    for (int kc = 0; kc < 2; ++kc) {
        if (kc == 0) WAITVM(4); else WAITVM(0);
        __builtin_amdgcn_s_barrier();
#pragma unroll
        for (int s2 = 0; s2 < 2; ++s2) {
            short8 af[4], bf8[2];
            const int cA = ((s2 * 4 + q) ^ (r16 & 7)) * 8;
#pragma unroll
            for (int t2 = 0; t2 < 4; ++t2)
                af[t2] = *(const short8*)&sm.s.A[kc][(wr * 64 + t2 * 16 + r16) * 64 + cA];
#pragma unroll
            for (int t2 = 0; t2 < 2; ++t2)
                bf8[t2] = *(const short8*)&sm.s.B[kc][(wc * 32 + t2 * 16 + r16) * 64 + cA];
#pragma unroll
            for (int ti = 0; ti < 4; ++ti)
#pragma unroll
                for (int tj = 0; tj < 2; ++tj)
                    acc[ti][tj] = __builtin_amdgcn_mfma_f32_16x16x32_bf16(
                        af[ti], bf8[tj], acc[ti][tj], 0, 0, 0);
        }
    }

    // mine val = sq[j] - 2*g (monotone in d2 for fixed i)
    float mp[4][4], mn[4][4];
#pragma unroll
    for (int ti = 0; ti < 4; ++ti)
#pragma unroll
        for (int p = 0; p < 4; ++p) { mp[ti][p] = NEG_BIG; mn[ti][p] = POS_BIG; }
    const bool diagblk = (blockIdx.x == blockIdx.y);
#pragma unroll
    for (int tj = 0; tj < 2; ++tj) {
#pragma unroll
        for (int ti = 0; ti < 4; ++ti)
#pragma unroll
            for (int p = 0; p < 4; ++p) {
                float val = fmaf(-2.0f, acc[ti][tj][p], sj[tj]);
                bool same = (li[ti][p] == lj[tj]);
                bool self = diagblk &&
                    ((wr * 64 + ti * 16 + q * 4 + p) == (wc * 32 + tj * 16 + r16));
                mp[ti][p] = fmaxf(mp[ti][p], (same && !self) ? val : NEG_BIG);
                mn[ti][p] = fminf(mn[ti][p], same ? POS_BIG : val);
            }
    }

    // LDS fold (aliases staging): 64 partials/row (16 lanes x 4 wc)
    __syncthreads();  // all frag reads done before aliasing overwrite
#pragma unroll
    for (int ti = 0; ti < 4; ++ti)
#pragma unroll
        for (int p = 0; p < 4; ++p) {
            int rloc = wr * 64 + ti * 16 + q * 4 + p;
            sm.f.mp[rloc][wc * 16 + r16] = mp[ti][p];
            sm.f.mn[rloc][wc * 16 + r16] = mn[ti][p];
        }
    __syncthreads();
    {
        int row = tid >> 2, part = tid & 3;  // 4 threads/row
        const float4* P = (const float4*)&sm.f.mp[row][part * 16];
        const float4* N = (const float4*)&sm.f.mn[row][part * 16];
        float4 p0 = P[0], p1 = P[1], p2 = P[2], p3 = P[3];
        float4 n0 = N[0], n1 = N[1], n2 = N[2], n3 = N[3];
        float M = fmaxf(fmaxf(fmaxf(p0.x, p0.y), fmaxf(p0.z, p0.w)),
                        fmaxf(fmaxf(p1.x, p1.y), fmaxf(p1.z, p1.w)));
        M = fmaxf(M, fmaxf(fmaxf(fmaxf(p2.x, p2.y), fmaxf(p2.z, p2.w)),
                           fmaxf(fmaxf(p3.x, p3.y), fmaxf(p3.z, p3.w))));
        float m_ = fminf(fminf(fminf(n0.x, n0.y), fminf(n0.z, n0.w)),
                         fminf(fminf(n1.x, n1.y), fminf(n1.z, n1.w)));
        m_ = fminf(m_, fminf(fminf(fminf(n2.x, n2.y), fminf(n2.z, n2.w)),
                             fminf(fminf(n3.x, n3.y), fminf(n3.z, n3.w))));
        M = fmaxf(M, __shfl_xor(M, 1));
        M = fmaxf(M, __shfl_xor(M, 2));
        m_ = fminf(m_, __shfl_xor(m_, 1));
        m_ = fminf(m_, __shfl_xor(m_, 2));
        if (part == 0) {
            pmp[(size_t)blockIdx.y * 4096 + i0 + row] = M;
            pmn[(size_t)blockIdx.y * 4096 + i0 + row] = m_;
        }
    }
}

// grid 16 x 256: fold 32 partials/row; validity from sentinels; ticket finalize.
__global__ __launch_bounds__(256) void tl_phase2(const float* __restrict__ pmp,
                                                 const float* __restrict__ pmn,
                                                 const float* __restrict__ sqn,
                                                 unsigned* __restrict__ cnt,
                                                 float* __restrict__ accum,
                                                 float* __restrict__ out) {
    __shared__ float sp[4], sv[4];
    int tid = threadIdx.x;
    int r = blockIdx.x * 256 + tid;
    float mp = NEG_BIG, mn = POS_BIG;
#pragma unroll
    for (int k = 0; k < 32; ++k) {
        mp = fmaxf(mp, pmp[(size_t)k * 4096 + r]);
        mn = fminf(mn, pmn[(size_t)k * 4096 + r]);
    }
    float si = sqn[r];
    bool valid = (mp > 0.5f * NEG_BIG) && (mn < 0.5f * POS_BIG);
    float hp = sqrtf(fmaxf(si + mp, 0.0f));
    float hn = sqrtf(fmaxf(si + mn, 0.0f));
    float pr = fmaxf(hp - hn + MARGIN_F, 0.0f);
    float s = valid ? pr : 0.0f;
    float n = valid ? 1.0f : 0.0f;
#pragma unroll
    for (int m = 1; m < 64; m <<= 1) {
        s += __shfl_xor(s, m);
        n += __shfl_xor(n, m);
    }
    if ((tid & 63) == 0) { sp[tid >> 6] = s; sv[tid >> 6] = n; }
    __syncthreads();
    if (tid == 0) {
        atomicAdd(&accum[0], sp[0] + sp[1] + sp[2] + sp[3]);
        atomicAdd(&accum[1], sv[0] + sv[1] + sv[2] + sv[3]);
        __threadfence();
        unsigned tk = atomicAdd(&cnt[2], 1u);
        if (tk == 15u) {
            float a = atomicAdd(&accum[0], 0.0f);  // coherent read
            float b = atomicAdd(&accum[1], 0.0f);
            out[0] = a / fmaxf(b, 1.0f);
        }
    }
}

extern "C" void kernel_launch(void* const* d_in, const int* in_sizes, int n_in,
                              void* d_out, int out_size, void* d_ws, size_t ws_size,
                              hipStream_t stream) {
    const float* E = (const float*)d_in[0];
    const int* labels = (const int*)d_in[1];
    float* out = (float*)d_out;

    // ws: Ebf 1 MB | pmp 512 KB | pmn 512 KB | sqn 16 KB | cnt/accum
    char* base = (char*)d_ws;
    unsigned short* Ebf = (unsigned short*)base;
    float* pmp = (float*)(base + (1u << 20));
    float* pmn = (float*)(base + (1u << 20) + (512u << 10));
    float* sqn = (float*)(base + (2u << 20));
    unsigned* cnt = (unsigned*)(base + (2u << 20) + (16u << 10));
    float* accum = (float*)(cnt + 8);

    tl_prep<<<512, 256, 0, stream>>>(E, Ebf, sqn, cnt);
    tl_phase1<<<dim3(32, 32), 512, 0, stream>>>(Ebf, labels, sqn, pmp, pmn);
    tl_phase2<<<16, 256, 0, stream>>>(pmp, pmn, sqn, cnt, accum, out);
}